// Round 9
// baseline (20.639 us; speedup 1.0000x reference)
//
#include <hip/hip_runtime.h>
#include <math.h>

// Problem constants: B=2, N=1024, H=128, E=32
#define NN 1024
#define PADW 132   // padded LDS row stride (words): uniform bank spread, f4-aligned

// Math:
//   t[bn,o]  = sum_h nf[bn,h]*Wt[o,h] + bt[o]
//   g[bn,e'] : e'=0..31  -> sum_o t[bn,o]*W1[e,o]     + b1[e]   (i-half)
//              e'=32..63 -> sum_o t[bn,o]*W1[e,128+o]           (j-half)
//   ew(n,m)  = b2 + sum_e relu(g[n,e] + g[m,32+e]) * W2[e]
//   out      = adj ? sigmoid(ew) : 0      (adj is exactly 0.0/1.0 by construction)
//
// ws layout: gall[2048*64] floats | mask[1024*32] u32 (bit m&31 of dword m>>5
// of row n = adj[n][m] != 0)

__device__ __forceinline__ float hsum4(float4 a) {
    return (a.x + a.y) + (a.z + a.w);
}

// k1: 512 blocks x 256 thr. Per block: pack 2 adj rows into bitmask, then
// compute g for 4 nodes (R8 body: s_w 33.8KB staged 3x: Wt-lo, Wt-hi, W1').
__global__ __launch_bounds__(256) void gall_kernel(
    const float* __restrict__ nf, const float* __restrict__ Wt,
    const float* __restrict__ bt, const float* __restrict__ W1,
    const float* __restrict__ b1, const float* __restrict__ adj,
    float* __restrict__ gall, unsigned* __restrict__ mask)
{
    __shared__ float s_w[64 * PADW];   // 33.8 KB staging buffer
    __shared__ float s_nf[4 * 128];
    __shared__ float s_t[4 * PADW];
    __shared__ float s_bt[128];
    __shared__ float s_b1[32];
    __shared__ unsigned s_nib[256];

    const int tid = threadIdx.x;
    const int bid = blockIdx.x;
    const int nb  = bid * 4;

    // ---- Phase 0: bitmask for adj rows 2*bid, 2*bid+1 (loads issued early) ----
    const float4 ar0 = *reinterpret_cast<const float4*>(adj + (2 * bid + 0) * NN + tid * 4);
    const float4 ar1 = *reinterpret_cast<const float4*>(adj + (2 * bid + 1) * NN + tid * 4);

    for (int idx = tid; idx < 4 * 128; idx += 256)
        s_nf[idx] = nf[nb * 128 + idx];
    if (tid < 128) s_bt[tid] = bt[tid];
    else if (tid < 160) s_b1[tid - 128] = b1[tid - 128];

    s_nib[tid] = (unsigned)(ar0.x != 0.f) | ((unsigned)(ar0.y != 0.f) << 1) |
                 ((unsigned)(ar0.z != 0.f) << 2) | ((unsigned)(ar0.w != 0.f) << 3);
    __syncthreads();
    if (tid < 32) {
        unsigned d = 0;
        #pragma unroll
        for (int k = 0; k < 8; ++k) d |= s_nib[8 * tid + k] << (4 * k);
        mask[(2 * bid + 0) * 32 + tid] = d;
    }
    __syncthreads();
    s_nib[tid] = (unsigned)(ar1.x != 0.f) | ((unsigned)(ar1.y != 0.f) << 1) |
                 ((unsigned)(ar1.z != 0.f) << 2) | ((unsigned)(ar1.w != 0.f) << 3);
    __syncthreads();
    if (tid < 32) {
        unsigned d = 0;
        #pragma unroll
        for (int k = 0; k < 8; ++k) d |= s_nib[8 * tid + k] << (4 * k);
        mask[(2 * bid + 1) * 32 + tid] = d;
    }

    const int n_own = tid >> 6;          // wave-uniform node 0..3
    const int o_own = tid & 63;

    // ---- Rounds 1+2: t = nf@Wt^T + bt, Wt staged in two 64-row halves ----
    #pragma unroll
    for (int hf = 0; hf < 2; ++hf) {
        __syncthreads();                 // protect s_w reuse
        for (int idx = tid; idx < 2048; idx += 256) {   // 64 rows x 32 float4
            const int o = idx >> 5, hc = idx & 31;
            *reinterpret_cast<float4*>(s_w + o * PADW + 4 * hc) =
                *reinterpret_cast<const float4*>(Wt + (hf * 64 + o) * 128 + 4 * hc);
        }
        __syncthreads();

        const float* wrow = s_w + o_own * PADW;
        const float* nrow = s_nf + n_own * 128;
        float4 A = {0.f, 0.f, 0.f, 0.f};
        #pragma unroll 8
        for (int hc = 0; hc < 32; ++hc) {
            const float4 w = *reinterpret_cast<const float4*>(wrow + 4 * hc);
            const float4 x = *reinterpret_cast<const float4*>(nrow + 4 * hc);
            A.x = fmaf(w.x, x.x, A.x);
            A.y = fmaf(w.y, x.y, A.y);
            A.z = fmaf(w.z, x.z, A.z);
            A.w = fmaf(w.w, x.w, A.w);
        }
        const int o = hf * 64 + o_own;
        s_t[n_own * PADW + o] = hsum4(A) + s_bt[o];
    }

    // ---- Round 3: g = t@W1'^T (+b1 on i-half) ----
    __syncthreads();
    for (int idx = tid; idx < 2048; idx += 256) {       // 64 ep-rows x 32 float4
        const int ep = idx >> 5, oc = idx & 31;
        const int e = ep & 31, half = ep >> 5;
        *reinterpret_cast<float4*>(s_w + ep * PADW + 4 * oc) =
            *reinterpret_cast<const float4*>(W1 + e * 256 + half * 128 + 4 * oc);
    }
    __syncthreads();
    {
        const int ep = tid & 63;
        const float* wrow = s_w + ep * PADW;
        const float* trow = s_t + n_own * PADW;
        float4 A = {0.f, 0.f, 0.f, 0.f};
        #pragma unroll 8
        for (int oc = 0; oc < 32; ++oc) {
            const float4 w = *reinterpret_cast<const float4*>(wrow + 4 * oc);
            const float4 x = *reinterpret_cast<const float4*>(trow + 4 * oc);
            A.x = fmaf(w.x, x.x, A.x);
            A.y = fmaf(w.y, x.y, A.y);
            A.z = fmaf(w.z, x.z, A.z);
            A.w = fmaf(w.w, x.w, A.w);
        }
        float g = hsum4(A);
        if ((ep >> 5) == 0) g += s_b1[ep & 31];
        gall[(nb + n_own) * 64 + ep] = g;   // lanes ep-consecutive -> coalesced
    }
}

// k2: one block per row n, BOTH batches. Mask-driven (no adj read, no atomics):
// popcount-prefix compaction -> dense worklist -> dense float4 stores.
__global__ __launch_bounds__(256) void edge_kernel(
    const float* __restrict__ gall, const unsigned* __restrict__ mask,
    const float* __restrict__ W2, const float* __restrict__ b2,
    float* __restrict__ out)
{
    const int n   = blockIdx.x;
    const int tid = threadIdx.x;

    __shared__ float s_u[2][32];
    __shared__ float s_w2[32];
    __shared__ unsigned s_mask[32];
    __shared__ unsigned s_pre[33];
    __shared__ unsigned short s_ent[NN];
    __shared__ float s_res[2 * NN];

    if (tid < 32)       s_u[0][tid]      = gall[n * 64 + tid];
    else if (tid < 64)  s_u[1][tid & 31] = gall[(NN + n) * 64 + (tid & 31)];
    else if (tid < 96)  s_w2[tid & 31]   = W2[tid & 31];
    else if (tid < 128) s_mask[tid & 31] = mask[n * 32 + (tid & 31)];
    __syncthreads();

    // exclusive popcount prefix over the 32 mask dwords (lane-independent O(32))
    if (tid < 32) {
        unsigned sum = 0;
        for (int d = 0; d < tid; ++d) sum += __popc(s_mask[d]);
        s_pre[tid] = sum;
        if (tid == 31) s_pre[32] = sum + __popc(s_mask[31]);
    }
    __syncthreads();

    const int m0 = tid * 4;
    const unsigned dw = s_mask[tid >> 3];
    int eidx[4];
    #pragma unroll
    for (int cc = 0; cc < 4; ++cc) {
        const int bitpos = 4 * (tid & 7) + cc;
        if ((dw >> bitpos) & 1u) {
            const int p = (int)s_pre[tid >> 3] + __popc(dw & ((1u << bitpos) - 1u));
            s_ent[p] = (unsigned short)(m0 + cc);
            eidx[cc] = p;
        } else {
            eidx[cc] = -1;
        }
    }
    __syncthreads();
    const int cnt = (int)s_pre[32];
    const float b2v = b2[0];

    for (int w = tid; w < 2 * cnt; w += 256) {
        const int bb = (w >= cnt);
        const int m  = s_ent[w - bb * cnt];
        const float* gj = gall + (bb * NN + m) * 64 + 32;   // contiguous 128B gather
        const float* uu = s_u[bb];
        float ew = b2v;
        #pragma unroll
        for (int j = 0; j < 8; ++j) {
            const float4 gv = *reinterpret_cast<const float4*>(gj + 4 * j);
            ew = fmaf(fmaxf(uu[4 * j + 0] + gv.x, 0.f), s_w2[4 * j + 0], ew);
            ew = fmaf(fmaxf(uu[4 * j + 1] + gv.y, 0.f), s_w2[4 * j + 1], ew);
            ew = fmaf(fmaxf(uu[4 * j + 2] + gv.z, 0.f), s_w2[4 * j + 2], ew);
            ew = fmaf(fmaxf(uu[4 * j + 3] + gv.w, 0.f), s_w2[4 * j + 3], ew);
        }
        s_res[w] = 1.f / (1.f + __expf(-ew));
    }
    __syncthreads();

    float4 r0, r1;
    float* rp0 = &r0.x;
    float* rp1 = &r1.x;
    #pragma unroll
    for (int cc = 0; cc < 4; ++cc) {
        if (eidx[cc] >= 0) {
            rp0[cc] = s_res[eidx[cc]];          // adj value is exactly 1.0 here
            rp1[cc] = s_res[cnt + eidx[cc]];
        } else {
            rp0[cc] = 0.f;
            rp1[cc] = 0.f;
        }
    }
    *reinterpret_cast<float4*>(out + (size_t)n * NN + m0) = r0;
    *reinterpret_cast<float4*>(out + (size_t)(NN + n) * NN + m0) = r1;
}

extern "C" void kernel_launch(void* const* d_in, const int* in_sizes, int n_in,
                              void* d_out, int out_size, void* d_ws, size_t ws_size,
                              hipStream_t stream)
{
    const float* nf  = (const float*)d_in[0];
    const float* adj = (const float*)d_in[1];
    const float* Wt  = (const float*)d_in[2];
    const float* bt  = (const float*)d_in[3];
    const float* W1  = (const float*)d_in[4];
    const float* b1  = (const float*)d_in[5];
    const float* W2  = (const float*)d_in[6];
    const float* b2  = (const float*)d_in[7];
    float* out  = (float*)d_out;
    float* gall = (float*)d_ws;                       // 2048*64 floats
    unsigned* mask = (unsigned*)(gall + 2048 * 64);   // 1024*32 u32

    hipLaunchKernelGGL(gall_kernel, dim3(512), dim3(256), 0, stream,
                       nf, Wt, bt, W1, b1, adj, gall, mask);
    hipLaunchKernelGGL(edge_kernel, dim3(NN), dim3(256), 0, stream,
                       gall, mask, W2, b2, out);
}

// Round 10
// 19.359 us; speedup vs baseline: 1.0661x; 1.0661x over previous
//
#include <hip/hip_runtime.h>
#include <math.h>

// Problem constants: B=2, N=1024, H=128, E=32
#define NN 1024
#define PADW 132   // padded LDS row stride (words): 132%32=4 -> uniform banks for
                   // lane-consecutive row access; 132%4==0 -> float4 aligned

// Math:
//   t[bn,o]  = sum_h nf[bn,h]*Wt[o,h] + bt[o]
//   g[bn,e'] : e'=0..31  -> sum_o t[bn,o]*W1[e, o]    + b1[e]   (i-half)
//              e'=32..63 -> sum_o t[bn,o]*W1[e, 128+o]          (j-half)
//   ew(n,m)  = b2 + sum_e relu(g[n,e] + g[m,32+e]) * W2[e]
//   out      = sigmoid(ew) * adj[n,m]   (exactly 0 where adj==0 -> skip)
// ws layout (floats): gall[2048*64]
//
// Final form (R10 = R4, best of 5 structural variants at 19.26us):
//  - two dispatches; intra-kernel grid sync measured at >=+8us on MI355X
//    (R3/R6/R7) so 2-dispatch is optimal here.
//  - k1: weights LDS-staged coalesced, conflict-free register-tiled dots.
//  - k2: one block per row, both batches; sparsity-compacted worklist
//    (~5% active edges) with dense lanes + dense float4 stores.

__device__ __forceinline__ float hsum4(float4 a) {
    return (a.x + a.y) + (a.z + a.w);
}

// k1: 256 blocks x 256 threads, 8 nodes/block.
__global__ __launch_bounds__(256) void gall_kernel(
    const float* __restrict__ nf, const float* __restrict__ Wt,
    const float* __restrict__ bt, const float* __restrict__ W1,
    const float* __restrict__ b1, float* __restrict__ gall)
{
    __shared__ float s_Wt[128 * PADW];  // Wt[o][h]
    __shared__ float s_W1[64 * PADW];   // W1'[ep][o], ep = half*32+e
    __shared__ float s_nf[8 * 128];
    __shared__ float s_t[8 * PADW];

    const int tid = threadIdx.x;
    const int nb  = blockIdx.x * 8;

    for (int idx = tid; idx < 128 * 128; idx += 256)
        s_Wt[(idx >> 7) * PADW + (idx & 127)] = Wt[idx];
    for (int idx = tid; idx < 32 * 256; idx += 256) {
        const int e = idx >> 8, j = idx & 255;
        const int half = j >> 7, o = j & 127;
        s_W1[(half * 32 + e) * PADW + o] = W1[idx];
    }
    for (int idx = tid; idx < 8 * 128; idx += 256)
        s_nf[idx] = nf[nb * 128 + idx];
    __syncthreads();

    // t-step: t[8][128]. thread: o = tid&127 (lane-consecutive -> uniform banks),
    // node group n0 = (tid>>7)*4. 1 Wt stream-read per 16 FMA.
    {
        const int o  = tid & 127;
        const int n0 = (tid >> 7) * 4;
        const float* wrow = s_Wt + o * PADW;
        float4 A0 = {0,0,0,0}, A1 = {0,0,0,0}, A2 = {0,0,0,0}, A3 = {0,0,0,0};
        #pragma unroll 8
        for (int hc = 0; hc < 32; ++hc) {
            const float4 w  = *reinterpret_cast<const float4*>(wrow + 4 * hc);
            const float4 x0 = *reinterpret_cast<const float4*>(s_nf + (n0 + 0) * 128 + 4 * hc);
            const float4 x1 = *reinterpret_cast<const float4*>(s_nf + (n0 + 1) * 128 + 4 * hc);
            const float4 x2 = *reinterpret_cast<const float4*>(s_nf + (n0 + 2) * 128 + 4 * hc);
            const float4 x3 = *reinterpret_cast<const float4*>(s_nf + (n0 + 3) * 128 + 4 * hc);
            A0.x = fmaf(w.x, x0.x, A0.x); A0.y = fmaf(w.y, x0.y, A0.y);
            A0.z = fmaf(w.z, x0.z, A0.z); A0.w = fmaf(w.w, x0.w, A0.w);
            A1.x = fmaf(w.x, x1.x, A1.x); A1.y = fmaf(w.y, x1.y, A1.y);
            A1.z = fmaf(w.z, x1.z, A1.z); A1.w = fmaf(w.w, x1.w, A1.w);
            A2.x = fmaf(w.x, x2.x, A2.x); A2.y = fmaf(w.y, x2.y, A2.y);
            A2.z = fmaf(w.z, x2.z, A2.z); A2.w = fmaf(w.w, x2.w, A2.w);
            A3.x = fmaf(w.x, x3.x, A3.x); A3.y = fmaf(w.y, x3.y, A3.y);
            A3.z = fmaf(w.z, x3.z, A3.z); A3.w = fmaf(w.w, x3.w, A3.w);
        }
        const float btv = bt[o];
        s_t[(n0 + 0) * PADW + o] = hsum4(A0) + btv;
        s_t[(n0 + 1) * PADW + o] = hsum4(A1) + btv;
        s_t[(n0 + 2) * PADW + o] = hsum4(A2) + btv;
        s_t[(n0 + 3) * PADW + o] = hsum4(A3) + btv;
    }
    __syncthreads();

    // g-step: g[8][64]. thread: ep = tid&63 (uniform banks), nodes n0 = (tid>>6)*2.
    {
        const int ep = tid & 63;
        const int n0 = (tid >> 6) * 2;
        const int e = ep & 31, half = ep >> 5;
        const float* w1row = s_W1 + ep * PADW;
        const float* t0 = s_t + (n0 + 0) * PADW;
        const float* t1 = s_t + (n0 + 1) * PADW;
        float4 A0 = {0,0,0,0}, A1 = {0,0,0,0};
        #pragma unroll 8
        for (int oc = 0; oc < 32; ++oc) {
            const float4 w  = *reinterpret_cast<const float4*>(w1row + 4 * oc);
            const float4 x0 = *reinterpret_cast<const float4*>(t0 + 4 * oc);
            const float4 x1 = *reinterpret_cast<const float4*>(t1 + 4 * oc);
            A0.x = fmaf(w.x, x0.x, A0.x); A0.y = fmaf(w.y, x0.y, A0.y);
            A0.z = fmaf(w.z, x0.z, A0.z); A0.w = fmaf(w.w, x0.w, A0.w);
            A1.x = fmaf(w.x, x1.x, A1.x); A1.y = fmaf(w.y, x1.y, A1.y);
            A1.z = fmaf(w.z, x1.z, A1.z); A1.w = fmaf(w.w, x1.w, A1.w);
        }
        float g0 = hsum4(A0), g1 = hsum4(A1);
        if (half == 0) { const float bv = b1[e]; g0 += bv; g1 += bv; }
        gall[(nb + n0 + 0) * 64 + ep] = g0;   // lanes ep-consecutive -> coalesced
        gall[(nb + n0 + 1) * 64 + ep] = g1;
    }
}

// k2: one block per row n, BOTH batches. LDS worklist compaction: dense lanes
// on the ~5% active edges, then dense float4 stores. Values keyed by entry
// index -> output deterministic regardless of wave ordering.
__global__ __launch_bounds__(256) void edge_kernel(
    const float* __restrict__ adj, const float* __restrict__ gall,
    const float* __restrict__ W2, const float* __restrict__ b2,
    float* __restrict__ out)
{
    const int n   = blockIdx.x;
    const int tid = threadIdx.x;

    __shared__ float s_u[2][32];
    __shared__ float s_w2[32];
    __shared__ unsigned s_cnt;
    __shared__ unsigned short s_ent[2048];
    __shared__ float s_res[2048];

    const int m0 = tid * 4;
    const float4 a4 = *reinterpret_cast<const float4*>(adj + n * NN + m0);  // shared by both b

    if (tid < 32)       s_u[0][tid]       = gall[n * 64 + tid];
    else if (tid < 64)  s_u[1][tid & 31]  = gall[(NN + n) * 64 + (tid & 31)];
    else if (tid < 96)  s_w2[tid & 31]    = W2[tid & 31];
    if (tid == 0) s_cnt = 0;
    __syncthreads();

    const float* ap = &a4.x;
    int eidx[8];
    #pragma unroll
    for (int b = 0; b < 2; ++b) {
        #pragma unroll
        for (int cc = 0; cc < 4; ++cc) {
            const int slot = b * 4 + cc;
            eidx[slot] = -1;
            if (ap[cc] != 0.f) {
                const unsigned w = atomicAdd(&s_cnt, 1u);
                s_ent[w] = (unsigned short)((b << 10) | (m0 + cc));
                eidx[slot] = (int)w;
            }
        }
    }
    __syncthreads();
    const unsigned cnt = s_cnt;
    const float b2v = b2[0];

    for (unsigned w = tid; w < cnt; w += 256) {
        const unsigned ent = s_ent[w];
        const int bb = ent >> 10, m = ent & 1023;
        const float* gj = gall + (bb * NN + m) * 64 + 32;   // contiguous 128B gather
        const float* uu = s_u[bb];
        float ew = b2v;
        #pragma unroll
        for (int j = 0; j < 8; ++j) {
            const float4 gv = *reinterpret_cast<const float4*>(gj + 4 * j);
            ew = fmaf(fmaxf(uu[4 * j + 0] + gv.x, 0.f), s_w2[4 * j + 0], ew);
            ew = fmaf(fmaxf(uu[4 * j + 1] + gv.y, 0.f), s_w2[4 * j + 1], ew);
            ew = fmaf(fmaxf(uu[4 * j + 2] + gv.z, 0.f), s_w2[4 * j + 2], ew);
            ew = fmaf(fmaxf(uu[4 * j + 3] + gv.w, 0.f), s_w2[4 * j + 3], ew);
        }
        s_res[w] = 1.f / (1.f + __expf(-ew));
    }
    __syncthreads();

    #pragma unroll
    for (int b = 0; b < 2; ++b) {
        float4 r4;
        float* rp = &r4.x;
        #pragma unroll
        for (int cc = 0; cc < 4; ++cc) {
            const int slot = b * 4 + cc;
            rp[cc] = (eidx[slot] >= 0) ? ap[cc] * s_res[eidx[slot]] : 0.f;
        }
        *reinterpret_cast<float4*>(out + (size_t)(b * NN + n) * NN + m0) = r4;
    }
}

extern "C" void kernel_launch(void* const* d_in, const int* in_sizes, int n_in,
                              void* d_out, int out_size, void* d_ws, size_t ws_size,
                              hipStream_t stream)
{
    const float* nf  = (const float*)d_in[0];
    const float* adj = (const float*)d_in[1];
    const float* Wt  = (const float*)d_in[2];
    const float* bt  = (const float*)d_in[3];
    const float* W1  = (const float*)d_in[4];
    const float* b1  = (const float*)d_in[5];
    const float* W2  = (const float*)d_in[6];
    const float* b2  = (const float*)d_in[7];
    float* out  = (float*)d_out;
    float* gall = (float*)d_ws;   // 2048*64 floats

    hipLaunchKernelGGL(gall_kernel, dim3(256), dim3(256), 0, stream,
                       nf, Wt, bt, W1, b1, gall);
    hipLaunchKernelGGL(edge_kernel, dim3(NN), dim3(256), 0, stream,
                       adj, gall, W2, b2, out);
}